// Round 7
// baseline (94.395 us; speedup 1.0000x reference)
//
#include <hip/hip_runtime.h>
#include <hip/hip_fp16.h>

#define BATCH   512
#define IN_DIM  16384
#define KNN     32

typedef __attribute__((ext_vector_type(4))) _Float16 half4v;

// ---------------------------------------------------------------------------
// Prep: pack knn (int32 -> uint16) and w (fp32 -> fp16) for all 3 layers.
// Shrinks the per-XCD-L2 replicated footprint of (knn,w) by 2x: the L2
// working set of layer 0 (slab 2MB + knn/w) drops from 5MB (>4MB L2, thrash)
// to ~3MB (resident).
// ---------------------------------------------------------------------------
#define N0 (8192 * KNN)
#define N1 (4096 * KNN)
#define N2 (2048 * KNN)
__global__ __launch_bounds__(256) void prep_k(const int* __restrict__ k0,
                                              const float* __restrict__ w0,
                                              const int* __restrict__ k1,
                                              const float* __restrict__ w1,
                                              const int* __restrict__ k2,
                                              const float* __restrict__ w2,
                                              unsigned short* __restrict__ ko,
                                              _Float16* __restrict__ wo) {
    const int t = blockIdx.x * 256 + threadIdx.x;
    if (t < N0) {
        ko[t] = (unsigned short)k0[t];
        wo[t] = (_Float16)w0[t];
    } else if (t < N0 + N1) {
        const int i = t - N0;
        ko[t] = (unsigned short)k1[i];
        wo[t] = (_Float16)w1[i];
    } else if (t < N0 + N1 + N2) {
        const int i = t - N0 - N1;
        ko[t] = (unsigned short)k2[i];
        wo[t] = (_Float16)w2[i];
    }
}

// ---------------------------------------------------------------------------
// Transpose x (BATCH, IN_DIM) fp32 -> xt (IN_DIM, BATCH) fp16.
// ---------------------------------------------------------------------------
__global__ __launch_bounds__(256) void transpose_h(const float* __restrict__ in,
                                                   _Float16* __restrict__ out) {
    __shared__ float tile[32][33];
    const int bx = blockIdx.x * 32;          // IN_DIM base
    const int by = blockIdx.y * 32;          // BATCH base
    const int tx = threadIdx.x & 31;
    const int ty = threadIdx.x >> 5;         // 0..7
#pragma unroll
    for (int j = 0; j < 32; j += 8)
        tile[ty + j][tx] = in[(size_t)(by + ty + j) * IN_DIM + bx + tx];
    __syncthreads();
    const int r = threadIdx.x >> 3;          // 0..31  (local d)
    const int c = (threadIdx.x & 7) * 4;     // local batch base
    half4v h;
    h[0] = (_Float16)tile[c + 0][r];
    h[1] = (_Float16)tile[c + 1][r];
    h[2] = (_Float16)tile[c + 2][r];
    h[3] = (_Float16)tile[c + 3][r];
    *(half4v*)(out + (size_t)(bx + r) * BATCH + by + c) = h;
}

// ---------------------------------------------------------------------------
// LCN layer (R6 structure: 1 feature x 64-batch chunk per wave, 4 waves/block,
// chunk-pure blocks, scalar knn/w path via readfirstlane) with:
//   - uint16 knn + fp16 w (halved scalar working set, stays on s_load path)
//   - non-temporal output stores (no L2 dirt from the 0-reuse store stream)
// ---------------------------------------------------------------------------
__global__ __launch_bounds__(256) void lcn_p4(const _Float16* __restrict__ xt,
                                              const _Float16* __restrict__ w,
                                              const float* __restrict__ bias,
                                              const unsigned short* __restrict__ knn,
                                              _Float16* __restrict__ yt) {
    const int lane = threadIdx.x & 63;
    const int wv   = __builtin_amdgcn_readfirstlane(threadIdx.x >> 6); // SGPR
    const int d    = (blockIdx.x >> 3) * 4 + wv;                       // scalar
    const int b    = (blockIdx.x & 7) * 64 + lane;
    const unsigned short* kp = knn + (size_t)d * KNN;
    const _Float16*       wp = w   + (size_t)d * KNN;
    const _Float16*       xb = xt + b;
    float acc = 0.f;
#pragma unroll
    for (int k = 0; k < KNN; ++k) {
        const int   idx = kp[k];                         // s_load (packed)
        const float wvv = (float)wp[k];                  // s_load (packed)
        acc += wvv * (float)xb[(size_t)idx * BATCH];     // 128B/wave, L2-resident
    }
    acc = fmaxf(acc + bias[d], 0.f);
    __builtin_nontemporal_store((_Float16)acc, yt + (size_t)d * BATCH + b);
}

// ---------------------------------------------------------------------------
// FC stage 1: partial sums over d-chunks of 256.
// ---------------------------------------------------------------------------
__global__ __launch_bounds__(256) void fc_partial(const _Float16* __restrict__ y2t,
                                                  const float* __restrict__ fcw,
                                                  float* __restrict__ part) {
    const int o  = blockIdx.x & 15;
    const int bh = (blockIdx.x >> 4) & 1;
    const int ch = blockIdx.x >> 5;          // 0..7
    const int b  = bh * 256 + threadIdx.x;
    const int d0 = ch * 256;
    float a0 = 0.f, a1 = 0.f, a2 = 0.f, a3 = 0.f;
#pragma unroll 4
    for (int d = d0; d < d0 + 256; d += 4) {
        a0 += (float)y2t[(size_t)(d + 0) * BATCH + b] * fcw[(d + 0) * 16 + o];
        a1 += (float)y2t[(size_t)(d + 1) * BATCH + b] * fcw[(d + 1) * 16 + o];
        a2 += (float)y2t[(size_t)(d + 2) * BATCH + b] * fcw[(d + 2) * 16 + o];
        a3 += (float)y2t[(size_t)(d + 3) * BATCH + b] * fcw[(d + 3) * 16 + o];
    }
    part[((size_t)b * 16 + o) * 8 + ch] = (a0 + a1) + (a2 + a3);
}

__global__ __launch_bounds__(256) void fc_final(const float* __restrict__ part,
                                                const float* __restrict__ fcb,
                                                float* __restrict__ out) {
    const int t = blockIdx.x * 256 + threadIdx.x;       // 0..8191
    const float4 p0 = *(const float4*)(part + (size_t)t * 8);
    const float4 p1 = *(const float4*)(part + (size_t)t * 8 + 4);
    out[t] = ((p0.x + p0.y) + (p0.z + p0.w)) + ((p1.x + p1.y) + (p1.z + p1.w))
             + fcb[t & 15];
}

extern "C" void kernel_launch(void* const* d_in, const int* in_sizes, int n_in,
                              void* d_out, int out_size, void* d_ws, size_t ws_size,
                              hipStream_t stream) {
    // setup_inputs() order: x, w0,b0,knn0, w1,b1,knn1, w2,b2,knn2, fc_w, fc_b
    const float* x    = (const float*)d_in[0];
    const float* w0   = (const float*)d_in[1];
    const float* b0   = (const float*)d_in[2];
    const int*   knn0 = (const int*)  d_in[3];
    const float* w1   = (const float*)d_in[4];
    const float* b1   = (const float*)d_in[5];
    const int*   knn1 = (const int*)  d_in[6];
    const float* w2   = (const float*)d_in[7];
    const float* b2   = (const float*)d_in[8];
    const int*   knn2 = (const int*)  d_in[9];
    const float* fcw  = (const float*)d_in[10];
    const float* fcb  = (const float*)d_in[11];
    float* out = (float*)d_out;

    // Workspace:
    //   xt   @  0 MB : 16 MB    y0t @ 16 MB : 8 MB
    //   y1t  @ 24 MB :  4 MB    y2t @ 28 MB : 2 MB
    //   part @ 30 MB : 256 KB
    //   ko   @ 30.5MB: 458752*2B = 0.875 MB   wo @ 31.5 MB: 0.875 MB
    char* ws = (char*)d_ws;
    _Float16*       xt   = (_Float16*)(ws);
    _Float16*       y0t  = (_Float16*)(ws + ((size_t)16 << 20));
    _Float16*       y1t  = (_Float16*)(ws + ((size_t)24 << 20));
    _Float16*       y2t  = (_Float16*)(ws + ((size_t)28 << 20));
    float*          part = (float*)   (ws + ((size_t)30 << 20));
    unsigned short* ko   = (unsigned short*)(ws + ((size_t)30 << 20) + ((size_t)512 << 10));
    _Float16*       wo   = (_Float16*)      (ws + ((size_t)31 << 20) + ((size_t)512 << 10));

    prep_k<<<(N0 + N1 + N2 + 255) / 256, 256, 0, stream>>>(knn0, w0, knn1, w1,
                                                           knn2, w2, ko, wo);
    transpose_h<<<dim3(IN_DIM / 32, BATCH / 32), 256, 0, stream>>>(x, xt);
    lcn_p4<<<(8192 / 4) * 8, 256, 0, stream>>>(xt,  wo,           b0, ko,           y0t);
    lcn_p4<<<(4096 / 4) * 8, 256, 0, stream>>>(y0t, wo + N0,      b1, ko + N0,      y1t);
    lcn_p4<<<(2048 / 4) * 8, 256, 0, stream>>>(y1t, wo + N0 + N1, b2, ko + N0 + N1, y2t);
    fc_partial<<<256, 256, 0, stream>>>(y2t, fcw, part);
    fc_final<<<32, 256, 0, stream>>>(part, fcb, out);
}

// Round 8
// 70.647 us; speedup vs baseline: 1.3362x; 1.3362x over previous
//
#include <hip/hip_runtime.h>
#include <hip/hip_fp16.h>

#define BATCH   512
#define IN_DIM  16384
#define KNN     32

typedef __attribute__((ext_vector_type(4))) _Float16 half4v;

#define N0 (8192 * KNN)
#define N1 (4096 * KNN)
#define N2 (2048 * KNN)

// ---------------------------------------------------------------------------
// Prep: pack (knn:int32, w:fp32) -> one uint32 per (d,k):
//   low 16 = index (prev_dim <= 16384 fits u16), high 16 = fp16(w) bits.
// Halves the per-XCD-replicated scalar working set (L0: 2MB -> 1MB) AND
// halves scalar-load traffic, while staying on the native dword s_load path
// (R7's u16/f16 scalar arrays fell off it -- SMEM has no sub-dword loads).
// ---------------------------------------------------------------------------
__global__ __launch_bounds__(256) void prep_k(const int* __restrict__ k0,
                                              const float* __restrict__ w0,
                                              const int* __restrict__ k1,
                                              const float* __restrict__ w1,
                                              const int* __restrict__ k2,
                                              const float* __restrict__ w2,
                                              unsigned int* __restrict__ po) {
    const int t = blockIdx.x * 256 + threadIdx.x;
    int idx; float wv;
    if (t < N0) {
        idx = k0[t];            wv = w0[t];
    } else if (t < N0 + N1) {
        idx = k1[t - N0];       wv = w1[t - N0];
    } else if (t < N0 + N1 + N2) {
        idx = k2[t - N0 - N1];  wv = w2[t - N0 - N1];
    } else {
        return;
    }
    const unsigned short hb =
        __builtin_bit_cast(unsigned short, (_Float16)wv);
    po[t] = (unsigned int)(unsigned short)idx | ((unsigned int)hb << 16);
}

// ---------------------------------------------------------------------------
// Transpose x (BATCH, IN_DIM) fp32 -> xt (IN_DIM, BATCH) fp16.
// ---------------------------------------------------------------------------
__global__ __launch_bounds__(256) void transpose_h(const float* __restrict__ in,
                                                   _Float16* __restrict__ out) {
    __shared__ float tile[32][33];
    const int bx = blockIdx.x * 32;          // IN_DIM base
    const int by = blockIdx.y * 32;          // BATCH base
    const int tx = threadIdx.x & 31;
    const int ty = threadIdx.x >> 5;         // 0..7
#pragma unroll
    for (int j = 0; j < 32; j += 8)
        tile[ty + j][tx] = in[(size_t)(by + ty + j) * IN_DIM + bx + tx];
    __syncthreads();
    const int r = threadIdx.x >> 3;          // 0..31  (local d)
    const int c = (threadIdx.x & 7) * 4;     // local batch base
    half4v h;
    h[0] = (_Float16)tile[c + 0][r];
    h[1] = (_Float16)tile[c + 1][r];
    h[2] = (_Float16)tile[c + 2][r];
    h[3] = (_Float16)tile[c + 3][r];
    *(half4v*)(out + (size_t)(bx + r) * BATCH + by + c) = h;
}

// ---------------------------------------------------------------------------
// LCN layer: R6's proven structure (1 feature x 64-batch chunk per wave,
// 4 waves/block, chunk-pure blocks via bid&7, scalar path forced with
// readfirstlane) + packed dword (idx,w) scalar stream.
// L0 per-XCD L2 set: slab 2MB + packed 1MB ~= 3MB < 4MB -> no thrash.
// ---------------------------------------------------------------------------
__global__ __launch_bounds__(256) void lcn_p4(const _Float16* __restrict__ xt,
                                              const unsigned int* __restrict__ packed,
                                              const float* __restrict__ bias,
                                              _Float16* __restrict__ yt) {
    const int lane = threadIdx.x & 63;
    const int wv   = __builtin_amdgcn_readfirstlane(threadIdx.x >> 6); // SGPR
    const int d    = (blockIdx.x >> 3) * 4 + wv;                       // scalar
    const int b    = (blockIdx.x & 7) * 64 + lane;
    const unsigned int* kp = packed + (size_t)d * KNN;
    const _Float16*     xb = xt + b;
    float acc = 0.f;
#pragma unroll
    for (int k = 0; k < KNN; ++k) {
        const unsigned int u = kp[k];                    // s_load dword
        const int idx = (int)(u & 0xffffu);              // SALU
        const _Float16 hw =
            __builtin_bit_cast(_Float16, (unsigned short)(u >> 16));
        acc += (float)hw * (float)xb[(size_t)idx * BATCH];  // 128B/wave gather
    }
    acc = fmaxf(acc + bias[d], 0.f);
    yt[(size_t)d * BATCH + b] = (_Float16)acc;
}

// ---------------------------------------------------------------------------
// FC stage 1: partial sums over d-chunks of 256.
// ---------------------------------------------------------------------------
__global__ __launch_bounds__(256) void fc_partial(const _Float16* __restrict__ y2t,
                                                  const float* __restrict__ fcw,
                                                  float* __restrict__ part) {
    const int o  = blockIdx.x & 15;
    const int bh = (blockIdx.x >> 4) & 1;
    const int ch = blockIdx.x >> 5;          // 0..7
    const int b  = bh * 256 + threadIdx.x;
    const int d0 = ch * 256;
    float a0 = 0.f, a1 = 0.f, a2 = 0.f, a3 = 0.f;
#pragma unroll 4
    for (int d = d0; d < d0 + 256; d += 4) {
        a0 += (float)y2t[(size_t)(d + 0) * BATCH + b] * fcw[(d + 0) * 16 + o];
        a1 += (float)y2t[(size_t)(d + 1) * BATCH + b] * fcw[(d + 1) * 16 + o];
        a2 += (float)y2t[(size_t)(d + 2) * BATCH + b] * fcw[(d + 2) * 16 + o];
        a3 += (float)y2t[(size_t)(d + 3) * BATCH + b] * fcw[(d + 3) * 16 + o];
    }
    part[((size_t)b * 16 + o) * 8 + ch] = (a0 + a1) + (a2 + a3);
}

__global__ __launch_bounds__(256) void fc_final(const float* __restrict__ part,
                                                const float* __restrict__ fcb,
                                                float* __restrict__ out) {
    const int t = blockIdx.x * 256 + threadIdx.x;       // 0..8191
    const float4 p0 = *(const float4*)(part + (size_t)t * 8);
    const float4 p1 = *(const float4*)(part + (size_t)t * 8 + 4);
    out[t] = ((p0.x + p0.y) + (p0.z + p0.w)) + ((p1.x + p1.y) + (p1.z + p1.w))
             + fcb[t & 15];
}

extern "C" void kernel_launch(void* const* d_in, const int* in_sizes, int n_in,
                              void* d_out, int out_size, void* d_ws, size_t ws_size,
                              hipStream_t stream) {
    // setup_inputs() order: x, w0,b0,knn0, w1,b1,knn1, w2,b2,knn2, fc_w, fc_b
    const float* x    = (const float*)d_in[0];
    const float* w0   = (const float*)d_in[1];
    const float* b0   = (const float*)d_in[2];
    const int*   knn0 = (const int*)  d_in[3];
    const float* w1   = (const float*)d_in[4];
    const float* b1   = (const float*)d_in[5];
    const int*   knn1 = (const int*)  d_in[6];
    const float* w2   = (const float*)d_in[7];
    const float* b2   = (const float*)d_in[8];
    const int*   knn2 = (const int*)  d_in[9];
    const float* fcw  = (const float*)d_in[10];
    const float* fcb  = (const float*)d_in[11];
    float* out = (float*)d_out;

    // Workspace:
    //   xt   @  0 MB : 16 MB    y0t @ 16 MB : 8 MB
    //   y1t  @ 24 MB :  4 MB    y2t @ 28 MB : 2 MB
    //   part @ 30 MB : 256 KB   packed @ 30.5 MB : 458752*4B = 1.75 MB
    char* ws = (char*)d_ws;
    _Float16*     xt   = (_Float16*)(ws);
    _Float16*     y0t  = (_Float16*)(ws + ((size_t)16 << 20));
    _Float16*     y1t  = (_Float16*)(ws + ((size_t)24 << 20));
    _Float16*     y2t  = (_Float16*)(ws + ((size_t)28 << 20));
    float*        part = (float*)   (ws + ((size_t)30 << 20));
    unsigned int* po   = (unsigned int*)(ws + ((size_t)30 << 20) + ((size_t)512 << 10));

    prep_k<<<(N0 + N1 + N2 + 255) / 256, 256, 0, stream>>>(knn0, w0, knn1, w1,
                                                           knn2, w2, po);
    transpose_h<<<dim3(IN_DIM / 32, BATCH / 32), 256, 0, stream>>>(x, xt);
    lcn_p4<<<(8192 / 4) * 8, 256, 0, stream>>>(xt,  po,           b0, y0t);
    lcn_p4<<<(4096 / 4) * 8, 256, 0, stream>>>(y0t, po + N0,      b1, y1t);
    lcn_p4<<<(2048 / 4) * 8, 256, 0, stream>>>(y1t, po + N0 + N1, b2, y2t);
    fc_partial<<<256, 256, 0, stream>>>(y2t, fcw, part);
    fc_final<<<32, 256, 0, stream>>>(part, fcb, out);
}